// Round 1
// baseline (1212.806 us; speedup 1.0000x reference)
//
#include <hip/hip_runtime.h>

// EPD GNN, factorized message passing, all-fp32.
//   h = enc(x|x_mask);  CSR built per call (count/scan/scatter, atomic cursor)
//   per repeat: Ps=h@W1s, Pd=h@W1d+b1; acc[d]=mean_e relu(Ps[s]+Pd[d]+ea@W1e) (incl self loop);
//   agg=acc@W2+b2; pre=relu(h@Wu1h+agg@Wu1a+gterm[batch]+bu1); h+=pre@Wu2+bu2; xg=segmean(h)
//   out = relu(h@Wd1+bd1)@Wd2+bd2

#define NN 50000
#define EE 400000
#define GG 8

// ---------------- zero kernels ----------------
__global__ void k_zero_f(float* __restrict__ p, int n) {
    int i = blockIdx.x * 256 + threadIdx.x;
    if (i < n) p[i] = 0.f;
}
__global__ void k_zero_i(int* __restrict__ p, int n) {
    int i = blockIdx.x * 256 + threadIdx.x;
    if (i < n) p[i] = 0;
}

// ---------------- CSR build ----------------
__global__ void k_count(const int* __restrict__ ei, int* __restrict__ deg) {
    int i = blockIdx.x * 256 + threadIdx.x;
    if (i < EE) atomicAdd(&deg[ei[EE + i]], 1);
}

__global__ __launch_bounds__(1024) void k_scan(const int* __restrict__ deg,
                                               int* __restrict__ row_ptr,
                                               int* __restrict__ cursor) {
    __shared__ int sdata[1024];
    __shared__ int scarry;
    const int t = threadIdx.x;
    if (t == 0) scarry = 0;
    __syncthreads();
    for (int base = 0; base < NN; base += 1024) {
        int v = (base + t < NN) ? deg[base + t] : 0;
        sdata[t] = v;
        __syncthreads();
        for (int off = 1; off < 1024; off <<= 1) {
            int x = (t >= off) ? sdata[t - off] : 0;
            __syncthreads();
            sdata[t] += x;
            __syncthreads();
        }
        int incl = sdata[t];
        int carry = scarry;
        if (base + t < NN) {
            int ex = carry + incl - v;
            row_ptr[base + t] = ex;
            cursor[base + t] = ex;
        }
        __syncthreads();
        if (t == 1023) scarry = carry + incl;
        __syncthreads();
    }
    if (t == 0) row_ptr[NN] = scarry;
}

__global__ void k_scatter(const int* __restrict__ ei, const float* __restrict__ ea,
                          int* __restrict__ cursor, int* __restrict__ src_sorted,
                          float4* __restrict__ ea_s) {
    int e = blockIdx.x * 256 + threadIdx.x;
    if (e >= EE) return;
    int s = ei[e], d = ei[EE + e];
    int p = atomicAdd(&cursor[d], 1);
    src_sorted[p] = s;
    ea_s[p] = make_float4(ea[3 * e], ea[3 * e + 1], ea[3 * e + 2], 0.f);
}

// ---------------- encoder layer 1 (K=8) ----------------
__global__ __launch_bounds__(256) void k_enc1(const float* __restrict__ x, const float* __restrict__ xm,
                                              const float* __restrict__ We1, const float* __restrict__ be1,
                                              float* __restrict__ t, int n) {
    __shared__ float w[8][128];
    __shared__ float b[128];
    int tid = threadIdx.x;
    for (int i = tid; i < 1024; i += 256) w[i >> 7][i & 127] = We1[i];
    if (tid < 128) b[tid] = be1[tid];
    __syncthreads();
    const int c = tid & 127, rp = tid >> 7;
    const int row0 = blockIdx.x * 32;
    for (int i = 0; i < 16; ++i) {
        int r = row0 + rp * 16 + i;
        if (r >= n) break;
        float i0 = x[r * 5 + 0], i1 = x[r * 5 + 1], i2 = x[r * 5 + 2], i3 = x[r * 5 + 3], i4 = x[r * 5 + 4];
        float m0 = xm[r * 3 + 0], m1 = xm[r * 3 + 1], m2 = xm[r * 3 + 2];
        float s = b[c] + i0 * w[0][c] + i1 * w[1][c] + i2 * w[2][c] + i3 * w[3][c] + i4 * w[4][c]
                + m0 * w[5][c] + m1 * w[6][c] + m2 * w[7][c];
        t[(size_t)r * 128 + c] = fmaxf(s, 0.f);
    }
}

// ---------------- main GEMM: out[M x 128] = op(A[M x 128] @ W[128 x 128]) ----------------
template <bool RELU, bool ACCUM, bool BIAS, bool GTERM>
__global__ __launch_bounds__(256) void gemm_k128(const float* __restrict__ A, const float* __restrict__ W,
                                                 const float* __restrict__ bias, const float* __restrict__ gt,
                                                 const int* __restrict__ batch, float* __restrict__ out, int M) {
    __shared__ float At[32][68];   // transposed A tile, pad->16B-aligned rows, 2-way-max banks
    __shared__ float Wt[32][128];
    const int tid = threadIdx.x;
    const int tr = tid >> 4;       // 0..15 (4 rows each)
    const int tc = tid & 15;       // 0..15 (cols tc*4 and 64+tc*4)
    const int row0 = blockIdx.x * 64;
    float acc[4][8];
#pragma unroll
    for (int i = 0; i < 4; ++i)
#pragma unroll
        for (int j = 0; j < 8; ++j) acc[i][j] = 0.f;

    for (int kk = 0; kk < 128; kk += 32) {
#pragma unroll
        for (int i = 0; i < 2; ++i) {
            int idx = tid + i * 256;
            int r = idx >> 3, c4 = (idx & 7) * 4;
            int rr = row0 + r;
            if (rr >= M) rr = M - 1;
            const float4 v = *(const float4*)(A + (size_t)rr * 128 + kk + c4);
            At[c4 + 0][r] = v.x; At[c4 + 1][r] = v.y; At[c4 + 2][r] = v.z; At[c4 + 3][r] = v.w;
        }
#pragma unroll
        for (int i = 0; i < 4; ++i) {
            int idx = tid + i * 256;
            int r = idx >> 5, c4 = (idx & 31) * 4;
            *(float4*)&Wt[r][c4] = *(const float4*)(W + (size_t)(kk + r) * 128 + c4);
        }
        __syncthreads();
#pragma unroll
        for (int k = 0; k < 32; ++k) {
            float4 a = *(const float4*)&At[k][tr * 4];
            float4 b0 = *(const float4*)&Wt[k][tc * 4];
            float4 b1 = *(const float4*)&Wt[k][64 + tc * 4];
            float av[4] = {a.x, a.y, a.z, a.w};
            float bv[8] = {b0.x, b0.y, b0.z, b0.w, b1.x, b1.y, b1.z, b1.w};
#pragma unroll
            for (int i = 0; i < 4; ++i)
#pragma unroll
                for (int j = 0; j < 8; ++j) acc[i][j] += av[i] * bv[j];
        }
        __syncthreads();
    }

    float4 bias0, bias1;
    if (BIAS) {
        bias0 = *(const float4*)(bias + tc * 4);
        bias1 = *(const float4*)(bias + 64 + tc * 4);
    }
#pragma unroll
    for (int i = 0; i < 4; ++i) {
        int r = row0 + tr * 4 + i;
        if (r >= M) continue;
        float o[8];
#pragma unroll
        for (int j = 0; j < 8; ++j) o[j] = acc[i][j];
        if (BIAS) {
            o[0] += bias0.x; o[1] += bias0.y; o[2] += bias0.z; o[3] += bias0.w;
            o[4] += bias1.x; o[5] += bias1.y; o[6] += bias1.z; o[7] += bias1.w;
        }
        if (GTERM) {
            int g = batch[r];
            const float4 g0 = *(const float4*)(gt + g * 128 + tc * 4);
            const float4 g1 = *(const float4*)(gt + g * 128 + 64 + tc * 4);
            o[0] += g0.x; o[1] += g0.y; o[2] += g0.z; o[3] += g0.w;
            o[4] += g1.x; o[5] += g1.y; o[6] += g1.z; o[7] += g1.w;
        }
        size_t off0 = (size_t)r * 128 + tc * 4;
        size_t off1 = off0 + 64;
        if (ACCUM) {
            float4 e0 = *(const float4*)(out + off0);
            float4 e1 = *(const float4*)(out + off1);
            o[0] += e0.x; o[1] += e0.y; o[2] += e0.z; o[3] += e0.w;
            o[4] += e1.x; o[5] += e1.y; o[6] += e1.z; o[7] += e1.w;
        }
        if (RELU) {
#pragma unroll
            for (int j = 0; j < 8; ++j) o[j] = fmaxf(o[j], 0.f);
        }
        *(float4*)(out + off0) = make_float4(o[0], o[1], o[2], o[3]);
        *(float4*)(out + off1) = make_float4(o[4], o[5], o[6], o[7]);
    }
}

// ---------------- edge aggregation: one wave per destination node ----------------
__global__ __launch_bounds__(256) void k_edge_agg(const float* __restrict__ Ps, const float* __restrict__ Pd,
                                                  const int* __restrict__ row_ptr, const int* __restrict__ src_sorted,
                                                  const float4* __restrict__ ea_s, const float* __restrict__ Wm1,
                                                  float* __restrict__ accm) {
    const int lane = threadIdx.x & 63;
    const int d = blockIdx.x * 4 + (threadIdx.x >> 6);
    const int c = lane * 2;
    const float2 w0 = *(const float2*)&Wm1[256 * 128 + c];
    const float2 w1 = *(const float2*)&Wm1[257 * 128 + c];
    const float2 w2 = *(const float2*)&Wm1[258 * 128 + c];
    const float2 pd = *(const float2*)&Pd[(size_t)d * 128 + c];
    const int beg = row_ptr[d], end = row_ptr[d + 1];
    // self loop (ea = 0)
    const float2 sv = *(const float2*)&Ps[(size_t)d * 128 + c];
    float ax = fmaxf(sv.x + pd.x, 0.f);
    float ay = fmaxf(sv.y + pd.y, 0.f);
    int k = beg;
    for (; k + 1 < end; k += 2) {
        int s0 = src_sorted[k], s1 = src_sorted[k + 1];
        float4 e0 = ea_s[k], e1 = ea_s[k + 1];
        float2 pa = *(const float2*)&Ps[(size_t)s0 * 128 + c];
        float2 pb = *(const float2*)&Ps[(size_t)s1 * 128 + c];
        float px0 = pa.x + pd.x + e0.x * w0.x + e0.y * w1.x + e0.z * w2.x;
        float py0 = pa.y + pd.y + e0.x * w0.y + e0.y * w1.y + e0.z * w2.y;
        float px1 = pb.x + pd.x + e1.x * w0.x + e1.y * w1.x + e1.z * w2.x;
        float py1 = pb.y + pd.y + e1.x * w0.y + e1.y * w1.y + e1.z * w2.y;
        ax += fmaxf(px0, 0.f) + fmaxf(px1, 0.f);
        ay += fmaxf(py0, 0.f) + fmaxf(py1, 0.f);
    }
    if (k < end) {
        int s0 = src_sorted[k];
        float4 e0 = ea_s[k];
        float2 pa = *(const float2*)&Ps[(size_t)s0 * 128 + c];
        float px0 = pa.x + pd.x + e0.x * w0.x + e0.y * w1.x + e0.z * w2.x;
        float py0 = pa.y + pd.y + e0.x * w0.y + e0.y * w1.y + e0.z * w2.y;
        ax += fmaxf(px0, 0.f);
        ay += fmaxf(py0, 0.f);
    }
    float inv = 1.f / (float)(end - beg + 1);
    *(float2*)&accm[(size_t)d * 128 + c] = make_float2(ax * inv, ay * inv);
}

// ---------------- per-graph stats ----------------
template <bool BC>
__global__ __launch_bounds__(256) void k_stats(const float* __restrict__ hmat, const float* __restrict__ xm,
                                               const int* __restrict__ batch, float* __restrict__ sum_h,
                                               float* __restrict__ sum_hbc, float* __restrict__ cnt_node,
                                               float* __restrict__ cnt_bc, int n) {
    const int c = threadIdx.x & 127;
    const int rp = threadIdx.x >> 7;
    const int rbase = blockIdx.x * 256 + rp * 128;
    float s = 0.f, sb = 0.f, cn = 0.f, cb = 0.f;
    int gcur = -1;
    for (int i = 0; i < 128; ++i) {
        int r = rbase + i;
        if (r >= n) break;
        int g = batch[r];
        if (g != gcur) {
            if (gcur >= 0) {
                atomicAdd(&sum_h[gcur * 128 + c], s);
                if (BC) {
                    atomicAdd(&sum_hbc[gcur * 128 + c], sb);
                    if (c == 0) {
                        atomicAdd(&cnt_node[gcur], cn);
                        atomicAdd(&cnt_bc[gcur], cb);
                    }
                }
            }
            gcur = g; s = 0.f; sb = 0.f; cn = 0.f; cb = 0.f;
        }
        float hv = hmat[(size_t)r * 128 + c];
        s += hv;
        if (BC) {
            float bc = xm[r * 3 + 2];
            sb += hv * bc;
            cn += 1.f;
            cb += bc;
        }
    }
    if (gcur >= 0) {
        atomicAdd(&sum_h[gcur * 128 + c], s);
        if (BC) {
            atomicAdd(&sum_hbc[gcur * 128 + c], sb);
            if (c == 0) {
                atomicAdd(&cnt_node[gcur], cn);
                atomicAdd(&cnt_bc[gcur], cb);
            }
        }
    }
}

__global__ void k_final_once(const float* __restrict__ sum_h, const float* __restrict__ sum_hbc,
                             const float* __restrict__ cnt_node, const float* __restrict__ cnt_bc,
                             float* __restrict__ xg, float* __restrict__ xbc) {
    int i = blockIdx.x * 256 + threadIdx.x;
    if (i < 1024) {
        int g = i >> 7;
        xg[i] = sum_h[i] / fmaxf(cnt_node[g], 1.f);
        xbc[i] = sum_hbc[i] / fmaxf(cnt_bc[g], 1.f);
    }
}

__global__ void k_final_xg(const float* __restrict__ sum_h, const float* __restrict__ cnt_node,
                           float* __restrict__ xg) {
    int i = blockIdx.x * 256 + threadIdx.x;
    if (i < 1024) xg[i] = sum_h[i] / fmaxf(cnt_node[i >> 7], 1.f);
}

// gterm[g] = xg[g] @ Wu1[256:384] + xbc[g] @ Wu1[384:512]
__global__ __launch_bounds__(128) void k_gterm(const float* __restrict__ xg, const float* __restrict__ xbc,
                                               const float* __restrict__ Wu1, float* __restrict__ gt) {
    const int g = blockIdx.x;
    const int c = threadIdx.x;
    __shared__ float sg[128], sb[128];
    sg[c] = xg[g * 128 + c];
    sb[c] = xbc[g * 128 + c];
    __syncthreads();
    float s = 0.f;
    for (int k = 0; k < 128; ++k) s += sg[k] * Wu1[(256 + k) * 128 + c];
    for (int k = 0; k < 128; ++k) s += sb[k] * Wu1[(384 + k) * 128 + c];
    gt[g * 128 + c] = s;
}

// ---------------- decoder layer 2 (128 -> 3), one wave per row ----------------
__global__ __launch_bounds__(256) void k_dec2(const float* __restrict__ t, const float* __restrict__ Wd2,
                                              const float* __restrict__ bd2, float* __restrict__ out, int n) {
    const int lane = threadIdx.x & 63;
    const int r = blockIdx.x * 4 + (threadIdx.x >> 6);
    if (r >= n) return;
    float p0 = 0.f, p1 = 0.f, p2 = 0.f;
    for (int k = lane; k < 128; k += 64) {
        float tv = t[(size_t)r * 128 + k];
        p0 += tv * Wd2[k * 3 + 0];
        p1 += tv * Wd2[k * 3 + 1];
        p2 += tv * Wd2[k * 3 + 2];
    }
    for (int off = 32; off; off >>= 1) {
        p0 += __shfl_down(p0, off);
        p1 += __shfl_down(p1, off);
        p2 += __shfl_down(p2, off);
    }
    if (lane == 0) {
        out[r * 3 + 0] = p0 + bd2[0];
        out[r * 3 + 1] = p1 + bd2[1];
        out[r * 3 + 2] = p2 + bd2[2];
    }
}

extern "C" void kernel_launch(void* const* d_in, const int* in_sizes, int n_in,
                              void* d_out, int out_size, void* d_ws, size_t ws_size,
                              hipStream_t stream) {
    const float* x = (const float*)d_in[0];
    const float* x_mask = (const float*)d_in[1];
    const float* edge_attr = (const float*)d_in[2];
    // d_in[3] = pos (unused)
    const float* W_e1 = (const float*)d_in[4];
    const float* b_e1 = (const float*)d_in[5];
    const float* W_e2 = (const float*)d_in[6];
    const float* b_e2 = (const float*)d_in[7];
    const float* W_m1 = (const float*)d_in[8];
    const float* b_m1 = (const float*)d_in[9];
    const float* W_m2 = (const float*)d_in[10];
    const float* b_m2 = (const float*)d_in[11];
    const float* W_u1 = (const float*)d_in[12];
    const float* b_u1 = (const float*)d_in[13];
    const float* W_u2 = (const float*)d_in[14];
    const float* b_u2 = (const float*)d_in[15];
    const float* W_d1 = (const float*)d_in[16];
    const float* b_d1 = (const float*)d_in[17];
    const float* W_d2 = (const float*)d_in[18];
    const float* b_d2 = (const float*)d_in[19];
    const int* edge_index = (const int*)d_in[20];
    const int* batch = (const int*)d_in[21];
    float* out = (float*)d_out;

    char* wp = (char*)d_ws;
    auto carve = [&](size_t bytes) {
        char* r = wp;
        wp += (bytes + 255) & ~(size_t)255;
        return r;
    };
    float* h = (float*)carve(sizeof(float) * (size_t)NN * 128);
    float* Ps = (float*)carve(sizeof(float) * (size_t)NN * 128);
    float* Pd = (float*)carve(sizeof(float) * (size_t)NN * 128);
    float* accm = (float*)carve(sizeof(float) * (size_t)NN * 128);
    float4* ea_s = (float4*)carve(sizeof(float4) * (size_t)EE);
    float* stats = (float*)carve(sizeof(float) * 5136);
    float* sum_h = stats;             // 1024
    float* sum_hbc = stats + 1024;    // 1024
    float* cnt_node = stats + 2048;   // 8
    float* cnt_bc = stats + 2056;     // 8
    float* xg_mean = stats + 2064;    // 1024
    float* xbc_mean = stats + 3088;   // 1024
    float* gterm = stats + 4112;      // 1024
    int* deg = (int*)carve(sizeof(int) * NN);
    int* row_ptr = (int*)carve(sizeof(int) * (NN + 1));
    int* cursor = (int*)carve(sizeof(int) * NN);
    int* src_sorted = (int*)carve(sizeof(int) * EE);

    const dim3 b256(256);
    const int gN256 = (NN + 255) / 256;   // 196
    const int gE256 = (EE + 255) / 256;   // 1563
    const int gGemm = (NN + 63) / 64;     // 782

    // setup: zero deg + stat accumulators (ws is poisoned each call)
    k_zero_i<<<gN256, b256, 0, stream>>>(deg, NN);
    k_zero_f<<<(2064 + 255) / 256, b256, 0, stream>>>(sum_h, 2064);
    // CSR
    k_count<<<gE256, b256, 0, stream>>>(edge_index, deg);
    k_scan<<<1, 1024, 0, stream>>>(deg, row_ptr, cursor);
    k_scatter<<<gE256, b256, 0, stream>>>(edge_index, edge_attr, cursor, src_sorted, ea_s);
    // encoder
    k_enc1<<<(NN + 31) / 32, b256, 0, stream>>>(x, x_mask, W_e1, b_e1, accm, NN);
    gemm_k128<false, false, true, false><<<gGemm, b256, 0, stream>>>(accm, W_e2, b_e2, nullptr, nullptr, h, NN);
    // per-graph stats (once): x_graph0, x_BC, counts
    k_stats<true><<<gN256, b256, 0, stream>>>(h, x_mask, batch, sum_h, sum_hbc, cnt_node, cnt_bc, NN);
    k_final_once<<<4, b256, 0, stream>>>(sum_h, sum_hbc, cnt_node, cnt_bc, xg_mean, xbc_mean);

    for (int rep = 0; rep < 3; ++rep) {
        k_gterm<<<GG, 128, 0, stream>>>(xg_mean, xbc_mean, W_u1, gterm);
        gemm_k128<false, false, false, false><<<gGemm, b256, 0, stream>>>(h, W_m1, nullptr, nullptr, nullptr, Ps, NN);
        gemm_k128<false, false, true, false><<<gGemm, b256, 0, stream>>>(h, W_m1 + 128 * 128, b_m1, nullptr, nullptr, Pd, NN);
        k_edge_agg<<<NN / 4, b256, 0, stream>>>(Ps, Pd, row_ptr, src_sorted, ea_s, W_m1, accm);
        // agg -> Ps (Ps dead after edge phase)
        gemm_k128<false, false, true, false><<<gGemm, b256, 0, stream>>>(accm, W_m2, b_m2, nullptr, nullptr, Ps, NN);
        // pre -> Pd
        gemm_k128<false, false, true, true><<<gGemm, b256, 0, stream>>>(h, W_u1, b_u1, gterm, batch, Pd, NN);
        // pre = relu(pre + agg @ Wu1[128:256])
        gemm_k128<true, true, false, false><<<gGemm, b256, 0, stream>>>(Ps, W_u1 + 128 * 128, nullptr, nullptr, nullptr, Pd, NN);
        // h += pre @ Wu2 + bu2
        gemm_k128<false, true, true, false><<<gGemm, b256, 0, stream>>>(Pd, W_u2, b_u2, nullptr, nullptr, h, NN);
        if (rep < 2) {
            k_zero_f<<<4, b256, 0, stream>>>(sum_h, 1024);
            k_stats<false><<<gN256, b256, 0, stream>>>(h, nullptr, batch, sum_h, nullptr, nullptr, nullptr, NN);
            k_final_xg<<<4, b256, 0, stream>>>(sum_h, cnt_node, xg_mean);
        }
    }
    // decoder
    gemm_k128<true, false, true, false><<<gGemm, b256, 0, stream>>>(h, W_d1, b_d1, nullptr, nullptr, accm, NN);
    k_dec2<<<NN / 4, b256, 0, stream>>>(accm, W_d2, b_d2, out, NN);
}

// Round 2
// 1085.415 us; speedup vs baseline: 1.1174x; 1.1174x over previous
//
#include <hip/hip_runtime.h>

// EPD GNN, factorized message passing, all-fp32.
//   h = enc(x|x_mask);  CSR built per call (count/3-phase scan/scatter)
//   per repeat: Ps=h@W1s, Pd=h@W1d+b1; acc[d]=mean_e relu(Ps[s]+Pd[d]+ea@W1e) (incl self loop);
//   agg=acc@W2+b2; pre=relu([h|agg]@Wu1[0:256]+gterm[batch]+bu1) (fused K=256);
//   h+=pre@Wu2+bu2; xg=segmean(h)
//   out = relu(h@Wd1+bd1)@Wd2+bd2

#define NN 50000
#define EE 400000
#define GG 8
#define NBLK 196   // ceil(NN/256)

// ---------------- CSR build ----------------
__global__ void k_count(const int* __restrict__ ei, int* __restrict__ deg) {
    int i = blockIdx.x * 256 + threadIdx.x;
    if (i < EE) atomicAdd(&deg[ei[EE + i]], 1);
}

// phase 1: per-block exclusive scan, block sums out
__global__ __launch_bounds__(256) void k_scan1(const int* __restrict__ deg, int* __restrict__ ex,
                                               int* __restrict__ blksum) {
    __shared__ int s[256];
    const int t = threadIdx.x;
    int i = blockIdx.x * 256 + t;
    int v = (i < NN) ? deg[i] : 0;
    s[t] = v;
    __syncthreads();
    for (int off = 1; off < 256; off <<= 1) {
        int x = (t >= off) ? s[t - off] : 0;
        __syncthreads();
        s[t] += x;
        __syncthreads();
    }
    if (i < NN) ex[i] = s[t] - v;
    if (t == 255) blksum[blockIdx.x] = s[255];
}

// phase 2: single-block exclusive scan of the 196 block sums (in place)
__global__ __launch_bounds__(256) void k_scan2(int* __restrict__ blksum) {
    __shared__ int s[256];
    const int t = threadIdx.x;
    int v = (t < NBLK) ? blksum[t] : 0;
    s[t] = v;
    __syncthreads();
    for (int off = 1; off < 256; off <<= 1) {
        int x = (t >= off) ? s[t - off] : 0;
        __syncthreads();
        s[t] += x;
        __syncthreads();
    }
    if (t < NBLK) blksum[t] = s[t] - v;
}

// phase 3: add block offsets -> row_ptr + cursor
__global__ void k_scan3(const int* __restrict__ ex, const int* __restrict__ blkoff,
                        int* __restrict__ row_ptr, int* __restrict__ cursor) {
    int i = blockIdx.x * 256 + threadIdx.x;
    if (i < NN) {
        int v = ex[i] + blkoff[blockIdx.x];
        row_ptr[i] = v;
        cursor[i] = v;
    }
    if (i == 0) row_ptr[NN] = EE;
}

__global__ void k_scatter(const int* __restrict__ ei, const float* __restrict__ ea,
                          int* __restrict__ cursor, int* __restrict__ src_sorted,
                          float4* __restrict__ ea_s) {
    int e = blockIdx.x * 256 + threadIdx.x;
    if (e >= EE) return;
    int s = ei[e], d = ei[EE + e];
    int p = atomicAdd(&cursor[d], 1);
    src_sorted[p] = s;
    ea_s[p] = make_float4(ea[3 * e], ea[3 * e + 1], ea[3 * e + 2], 0.f);
}

// ---------------- encoder layer 1 (K=8) ----------------
__global__ __launch_bounds__(256) void k_enc1(const float* __restrict__ x, const float* __restrict__ xm,
                                              const float* __restrict__ We1, const float* __restrict__ be1,
                                              float* __restrict__ t, int n) {
    __shared__ float w[8][128];
    __shared__ float b[128];
    int tid = threadIdx.x;
    for (int i = tid; i < 1024; i += 256) w[i >> 7][i & 127] = We1[i];
    if (tid < 128) b[tid] = be1[tid];
    __syncthreads();
    const int c = tid & 127, rp = tid >> 7;
    const int row0 = blockIdx.x * 32;
    for (int i = 0; i < 16; ++i) {
        int r = row0 + rp * 16 + i;
        if (r >= n) break;
        float i0 = x[r * 5 + 0], i1 = x[r * 5 + 1], i2 = x[r * 5 + 2], i3 = x[r * 5 + 3], i4 = x[r * 5 + 4];
        float m0 = xm[r * 3 + 0], m1 = xm[r * 3 + 1], m2 = xm[r * 3 + 2];
        float s = b[c] + i0 * w[0][c] + i1 * w[1][c] + i2 * w[2][c] + i3 * w[3][c] + i4 * w[4][c]
                + m0 * w[5][c] + m1 * w[6][c] + m2 * w[7][c];
        t[(size_t)r * 128 + c] = fmaxf(s, 0.f);
    }
}

// ---------------- main GEMM: out[M x 128] = op([A|A2][M x K] @ W[K x 128]) ----------------
// K2=false: K=128, A only. K2=true: K=256, first 128 from A, second 128 from A2.
template <bool RELU, bool ACCUM, bool BIAS, bool GTERM, bool K2>
__global__ __launch_bounds__(256) void gemm_k128(const float* __restrict__ A, const float* __restrict__ A2,
                                                 const float* __restrict__ W,
                                                 const float* __restrict__ bias, const float* __restrict__ gt,
                                                 const int* __restrict__ batch, float* __restrict__ out, int M) {
    __shared__ float At[32][68];   // transposed A tile
    __shared__ float Wt[32][128];
    const int tid = threadIdx.x;
    const int tr = tid >> 4;       // 0..15 (4 rows each)
    const int tc = tid & 15;       // 0..15 (cols tc*4 and 64+tc*4)
    const int row0 = blockIdx.x * 64;
    float acc[4][8];
#pragma unroll
    for (int i = 0; i < 4; ++i)
#pragma unroll
        for (int j = 0; j < 8; ++j) acc[i][j] = 0.f;

    const int KTOT = K2 ? 256 : 128;
    for (int kk = 0; kk < KTOT; kk += 32) {
        const float* Asrc = (!K2 || kk < 128) ? A : A2;
        const int kof = (!K2 || kk < 128) ? kk : kk - 128;
#pragma unroll
        for (int i = 0; i < 2; ++i) {
            int idx = tid + i * 256;
            int r = idx >> 3, c4 = (idx & 7) * 4;
            int rr = row0 + r;
            if (rr >= M) rr = M - 1;
            const float4 v = *(const float4*)(Asrc + (size_t)rr * 128 + kof + c4);
            At[c4 + 0][r] = v.x; At[c4 + 1][r] = v.y; At[c4 + 2][r] = v.z; At[c4 + 3][r] = v.w;
        }
#pragma unroll
        for (int i = 0; i < 4; ++i) {
            int idx = tid + i * 256;
            int r = idx >> 5, c4 = (idx & 31) * 4;
            *(float4*)&Wt[r][c4] = *(const float4*)(W + (size_t)(kk + r) * 128 + c4);
        }
        __syncthreads();
#pragma unroll
        for (int k = 0; k < 32; ++k) {
            float4 a = *(const float4*)&At[k][tr * 4];
            float4 b0 = *(const float4*)&Wt[k][tc * 4];
            float4 b1 = *(const float4*)&Wt[k][64 + tc * 4];
            float av[4] = {a.x, a.y, a.z, a.w};
            float bv[8] = {b0.x, b0.y, b0.z, b0.w, b1.x, b1.y, b1.z, b1.w};
#pragma unroll
            for (int i = 0; i < 4; ++i)
#pragma unroll
                for (int j = 0; j < 8; ++j) acc[i][j] += av[i] * bv[j];
        }
        __syncthreads();
    }

    float4 bias0, bias1;
    if (BIAS) {
        bias0 = *(const float4*)(bias + tc * 4);
        bias1 = *(const float4*)(bias + 64 + tc * 4);
    }
#pragma unroll
    for (int i = 0; i < 4; ++i) {
        int r = row0 + tr * 4 + i;
        if (r >= M) continue;
        float o[8];
#pragma unroll
        for (int j = 0; j < 8; ++j) o[j] = acc[i][j];
        if (BIAS) {
            o[0] += bias0.x; o[1] += bias0.y; o[2] += bias0.z; o[3] += bias0.w;
            o[4] += bias1.x; o[5] += bias1.y; o[6] += bias1.z; o[7] += bias1.w;
        }
        if (GTERM) {
            int g = batch[r];
            const float4 g0 = *(const float4*)(gt + g * 128 + tc * 4);
            const float4 g1 = *(const float4*)(gt + g * 128 + 64 + tc * 4);
            o[0] += g0.x; o[1] += g0.y; o[2] += g0.z; o[3] += g0.w;
            o[4] += g1.x; o[5] += g1.y; o[6] += g1.z; o[7] += g1.w;
        }
        size_t off0 = (size_t)r * 128 + tc * 4;
        size_t off1 = off0 + 64;
        if (ACCUM) {
            float4 e0 = *(const float4*)(out + off0);
            float4 e1 = *(const float4*)(out + off1);
            o[0] += e0.x; o[1] += e0.y; o[2] += e0.z; o[3] += e0.w;
            o[4] += e1.x; o[5] += e1.y; o[6] += e1.z; o[7] += e1.w;
        }
        if (RELU) {
#pragma unroll
            for (int j = 0; j < 8; ++j) o[j] = fmaxf(o[j], 0.f);
        }
        *(float4*)(out + off0) = make_float4(o[0], o[1], o[2], o[3]);
        *(float4*)(out + off1) = make_float4(o[4], o[5], o[6], o[7]);
    }
}

// ---------------- edge aggregation: one wave per destination node ----------------
__global__ __launch_bounds__(256) void k_edge_agg(const float* __restrict__ Ps, const float* __restrict__ Pd,
                                                  const int* __restrict__ row_ptr, const int* __restrict__ src_sorted,
                                                  const float4* __restrict__ ea_s, const float* __restrict__ Wm1,
                                                  float* __restrict__ accm) {
    const int lane = threadIdx.x & 63;
    const int d = blockIdx.x * 4 + (threadIdx.x >> 6);
    const int c = lane * 2;
    const float2 w0 = *(const float2*)&Wm1[256 * 128 + c];
    const float2 w1 = *(const float2*)&Wm1[257 * 128 + c];
    const float2 w2 = *(const float2*)&Wm1[258 * 128 + c];
    const float2 pd = *(const float2*)&Pd[(size_t)d * 128 + c];
    const int beg = row_ptr[d], end = row_ptr[d + 1];
    // self loop (ea = 0)
    const float2 sv = *(const float2*)&Ps[(size_t)d * 128 + c];
    float ax = fmaxf(sv.x + pd.x, 0.f);
    float ay = fmaxf(sv.y + pd.y, 0.f);
    int k = beg;
    for (; k + 1 < end; k += 2) {
        int s0 = src_sorted[k], s1 = src_sorted[k + 1];
        float4 e0 = ea_s[k], e1 = ea_s[k + 1];
        float2 pa = *(const float2*)&Ps[(size_t)s0 * 128 + c];
        float2 pb = *(const float2*)&Ps[(size_t)s1 * 128 + c];
        float px0 = pa.x + pd.x + e0.x * w0.x + e0.y * w1.x + e0.z * w2.x;
        float py0 = pa.y + pd.y + e0.x * w0.y + e0.y * w1.y + e0.z * w2.y;
        float px1 = pb.x + pd.x + e1.x * w0.x + e1.y * w1.x + e1.z * w2.x;
        float py1 = pb.y + pd.y + e1.x * w0.y + e1.y * w1.y + e1.z * w2.y;
        ax += fmaxf(px0, 0.f) + fmaxf(px1, 0.f);
        ay += fmaxf(py0, 0.f) + fmaxf(py1, 0.f);
    }
    if (k < end) {
        int s0 = src_sorted[k];
        float4 e0 = ea_s[k];
        float2 pa = *(const float2*)&Ps[(size_t)s0 * 128 + c];
        float px0 = pa.x + pd.x + e0.x * w0.x + e0.y * w1.x + e0.z * w2.x;
        float py0 = pa.y + pd.y + e0.x * w0.y + e0.y * w1.y + e0.z * w2.y;
        ax += fmaxf(px0, 0.f);
        ay += fmaxf(py0, 0.f);
    }
    float inv = 1.f / (float)(end - beg + 1);
    *(float2*)&accm[(size_t)d * 128 + c] = make_float2(ax * inv, ay * inv);
}

// ---------------- per-graph stats ----------------
template <bool BC>
__global__ __launch_bounds__(256) void k_stats(const float* __restrict__ hmat, const float* __restrict__ xm,
                                               const int* __restrict__ batch, float* __restrict__ sum_h,
                                               float* __restrict__ sum_hbc, float* __restrict__ cnt_node,
                                               float* __restrict__ cnt_bc, int n) {
    const int c = threadIdx.x & 127;
    const int rp = threadIdx.x >> 7;
    const int rbase = blockIdx.x * 256 + rp * 128;
    float s = 0.f, sb = 0.f, cn = 0.f, cb = 0.f;
    int gcur = -1;
    for (int i = 0; i < 128; ++i) {
        int r = rbase + i;
        if (r >= n) break;
        int g = batch[r];
        if (g != gcur) {
            if (gcur >= 0) {
                atomicAdd(&sum_h[gcur * 128 + c], s);
                if (BC) {
                    atomicAdd(&sum_hbc[gcur * 128 + c], sb);
                    if (c == 0) {
                        atomicAdd(&cnt_node[gcur], cn);
                        atomicAdd(&cnt_bc[gcur], cb);
                    }
                }
            }
            gcur = g; s = 0.f; sb = 0.f; cn = 0.f; cb = 0.f;
        }
        float hv = hmat[(size_t)r * 128 + c];
        s += hv;
        if (BC) {
            float bc = xm[r * 3 + 2];
            sb += hv * bc;
            cn += 1.f;
            cb += bc;
        }
    }
    if (gcur >= 0) {
        atomicAdd(&sum_h[gcur * 128 + c], s);
        if (BC) {
            atomicAdd(&sum_hbc[gcur * 128 + c], sb);
            if (c == 0) {
                atomicAdd(&cnt_node[gcur], cn);
                atomicAdd(&cnt_bc[gcur], cb);
            }
        }
    }
}

// gterm[g] = mean_h[g] @ Wu1[256:384] + mean_hbc[g] @ Wu1[384:512]   (division folded in)
__global__ __launch_bounds__(128) void k_gterm(const float* __restrict__ sum_h, const float* __restrict__ sum_hbc,
                                               const float* __restrict__ cnt_node, const float* __restrict__ cnt_bc,
                                               const float* __restrict__ Wu1, float* __restrict__ gt) {
    const int g = blockIdx.x;
    const int c = threadIdx.x;
    __shared__ float sg[128], sb[128];
    const float invn = 1.f / fmaxf(cnt_node[g], 1.f);
    const float invb = 1.f / fmaxf(cnt_bc[g], 1.f);
    sg[c] = sum_h[g * 128 + c] * invn;
    sb[c] = sum_hbc[g * 128 + c] * invb;
    __syncthreads();
    float s = 0.f;
    for (int k = 0; k < 128; ++k) s += sg[k] * Wu1[(256 + k) * 128 + c];
    for (int k = 0; k < 128; ++k) s += sb[k] * Wu1[(384 + k) * 128 + c];
    gt[g * 128 + c] = s;
}

// ---------------- decoder layer 2 (128 -> 3), one wave per row ----------------
__global__ __launch_bounds__(256) void k_dec2(const float* __restrict__ t, const float* __restrict__ Wd2,
                                              const float* __restrict__ bd2, float* __restrict__ out, int n) {
    const int lane = threadIdx.x & 63;
    const int r = blockIdx.x * 4 + (threadIdx.x >> 6);
    if (r >= n) return;
    float p0 = 0.f, p1 = 0.f, p2 = 0.f;
    for (int k = lane; k < 128; k += 64) {
        float tv = t[(size_t)r * 128 + k];
        p0 += tv * Wd2[k * 3 + 0];
        p1 += tv * Wd2[k * 3 + 1];
        p2 += tv * Wd2[k * 3 + 2];
    }
    for (int off = 32; off; off >>= 1) {
        p0 += __shfl_down(p0, off);
        p1 += __shfl_down(p1, off);
        p2 += __shfl_down(p2, off);
    }
    if (lane == 0) {
        out[r * 3 + 0] = p0 + bd2[0];
        out[r * 3 + 1] = p1 + bd2[1];
        out[r * 3 + 2] = p2 + bd2[2];
    }
}

extern "C" void kernel_launch(void* const* d_in, const int* in_sizes, int n_in,
                              void* d_out, int out_size, void* d_ws, size_t ws_size,
                              hipStream_t stream) {
    const float* x = (const float*)d_in[0];
    const float* x_mask = (const float*)d_in[1];
    const float* edge_attr = (const float*)d_in[2];
    // d_in[3] = pos (unused)
    const float* W_e1 = (const float*)d_in[4];
    const float* b_e1 = (const float*)d_in[5];
    const float* W_e2 = (const float*)d_in[6];
    const float* b_e2 = (const float*)d_in[7];
    const float* W_m1 = (const float*)d_in[8];
    const float* b_m1 = (const float*)d_in[9];
    const float* W_m2 = (const float*)d_in[10];
    const float* b_m2 = (const float*)d_in[11];
    const float* W_u1 = (const float*)d_in[12];
    const float* b_u1 = (const float*)d_in[13];
    const float* W_u2 = (const float*)d_in[14];
    const float* b_u2 = (const float*)d_in[15];
    const float* W_d1 = (const float*)d_in[16];
    const float* b_d1 = (const float*)d_in[17];
    const float* W_d2 = (const float*)d_in[18];
    const float* b_d2 = (const float*)d_in[19];
    const int* edge_index = (const int*)d_in[20];
    const int* batch = (const int*)d_in[21];
    float* out = (float*)d_out;

    char* wp = (char*)d_ws;
    auto carve = [&](size_t bytes) {
        char* r = wp;
        wp += (bytes + 255) & ~(size_t)255;
        return r;
    };
    float* h = (float*)carve(sizeof(float) * (size_t)NN * 128);
    float* Ps = (float*)carve(sizeof(float) * (size_t)NN * 128);
    float* Pd = (float*)carve(sizeof(float) * (size_t)NN * 128);
    float* accm = (float*)carve(sizeof(float) * (size_t)NN * 128);
    float4* ea_s = (float4*)carve(sizeof(float4) * (size_t)EE);
    float* stats = (float*)carve(sizeof(float) * 4096);
    float* sum_h = stats;             // 1024
    float* sum_hbc = stats + 1024;    // 1024
    float* cnt_node = stats + 2048;   // 8
    float* cnt_bc = stats + 2056;     // 8
    float* gterm = stats + 2304;      // 1024
    int* deg = (int*)carve(sizeof(int) * NN);
    int* row_ptr = (int*)carve(sizeof(int) * (NN + 1));
    int* cursor = (int*)carve(sizeof(int) * NN);
    int* src_sorted = (int*)carve(sizeof(int) * EE);
    int* exbuf = (int*)carve(sizeof(int) * NN);
    int* blksum = (int*)carve(sizeof(int) * 256);

    const dim3 b256(256);
    const int gE256 = (EE + 255) / 256;   // 1563
    const int gGemm = (NN + 63) / 64;     // 782

    // zero deg + stat accumulators via memset (graph-capture safe)
    hipMemsetAsync(deg, 0, sizeof(int) * NN, stream);
    hipMemsetAsync(stats, 0, sizeof(float) * 2064, stream);
    // CSR
    k_count<<<gE256, b256, 0, stream>>>(edge_index, deg);
    k_scan1<<<NBLK, b256, 0, stream>>>(deg, exbuf, blksum);
    k_scan2<<<1, b256, 0, stream>>>(blksum);
    k_scan3<<<NBLK, b256, 0, stream>>>(exbuf, blksum, row_ptr, cursor);
    k_scatter<<<gE256, b256, 0, stream>>>(edge_index, edge_attr, cursor, src_sorted, ea_s);
    // encoder
    k_enc1<<<(NN + 31) / 32, b256, 0, stream>>>(x, x_mask, W_e1, b_e1, accm, NN);
    gemm_k128<false, false, true, false, false><<<gGemm, b256, 0, stream>>>(accm, nullptr, W_e2, b_e2, nullptr, nullptr, h, NN);
    // per-graph stats (once): sums for x_graph0, x_BC, counts
    k_stats<true><<<NBLK, b256, 0, stream>>>(h, x_mask, batch, sum_h, sum_hbc, cnt_node, cnt_bc, NN);

    for (int rep = 0; rep < 3; ++rep) {
        k_gterm<<<GG, 128, 0, stream>>>(sum_h, sum_hbc, cnt_node, cnt_bc, W_u1, gterm);
        gemm_k128<false, false, false, false, false><<<gGemm, b256, 0, stream>>>(h, nullptr, W_m1, nullptr, nullptr, nullptr, Ps, NN);
        gemm_k128<false, false, true, false, false><<<gGemm, b256, 0, stream>>>(h, nullptr, W_m1 + 128 * 128, b_m1, nullptr, nullptr, Pd, NN);
        k_edge_agg<<<NN / 4, b256, 0, stream>>>(Ps, Pd, row_ptr, src_sorted, ea_s, W_m1, accm);
        // agg = accm @ W_m2 + b_m2 -> Ps (dead after edge phase)
        gemm_k128<false, false, true, false, false><<<gGemm, b256, 0, stream>>>(accm, nullptr, W_m2, b_m2, nullptr, nullptr, Ps, NN);
        // pre = relu([h|agg] @ Wu1[0:256] + gterm[batch] + b_u1) -> Pd   (fused K=256)
        gemm_k128<true, false, true, true, true><<<gGemm, b256, 0, stream>>>(h, Ps, W_u1, b_u1, gterm, batch, Pd, NN);
        // h += pre @ Wu2 + bu2
        gemm_k128<false, true, true, false, false><<<gGemm, b256, 0, stream>>>(Pd, nullptr, W_u2, b_u2, nullptr, nullptr, h, NN);
        if (rep < 2) {
            hipMemsetAsync(sum_h, 0, sizeof(float) * 1024, stream);
            k_stats<false><<<NBLK, b256, 0, stream>>>(h, nullptr, batch, sum_h, nullptr, nullptr, nullptr, NN);
        }
    }
    // decoder
    gemm_k128<true, false, true, false, false><<<gGemm, b256, 0, stream>>>(h, nullptr, W_d1, b_d1, nullptr, nullptr, accm, NN);
    k_dec2<<<NN / 4, b256, 0, stream>>>(accm, W_d2, b_d2, out, NN);
}

// Round 3
// 940.924 us; speedup vs baseline: 1.2890x; 1.1536x over previous
//
#include <hip/hip_runtime.h>

// EPD GNN, factorized message passing, all-fp32.
//   h = enc(x|x_mask);  CSR built per call (count/3-phase scan/scatter)
//   per repeat: Ps=h@W1s, Pd=h@W1d+b1; acc[d]=mean_e relu(Ps[s]+Pd[d]+ea@W1e) (incl self loop);
//   agg=acc@W2+b2; pre=relu([h|agg]@Wu1[0:256]+gterm[batch]+bu1) (fused K=256);
//   h+=pre@Wu2+bu2 (STATS fused: per-graph column sums in epilogue); out = relu(h@Wd1+bd1)@Wd2+bd2

#define NN 50000
#define EE 400000
#define GG 8
#define NBLK 196    // ceil(NN/256)
#define GB128 391   // ceil(NN/128)
#define GB64 782    // ceil(NN/64)

// ---------------- CSR build ----------------
__global__ void k_count(const int* __restrict__ ei, int* __restrict__ deg) {
    int i = blockIdx.x * 256 + threadIdx.x;
    if (i < EE) atomicAdd(&deg[ei[EE + i]], 1);
}

__global__ __launch_bounds__(256) void k_scan1(const int* __restrict__ deg, int* __restrict__ ex,
                                               int* __restrict__ blksum) {
    __shared__ int s[256];
    const int t = threadIdx.x;
    int i = blockIdx.x * 256 + t;
    int v = (i < NN) ? deg[i] : 0;
    s[t] = v;
    __syncthreads();
    for (int off = 1; off < 256; off <<= 1) {
        int x = (t >= off) ? s[t - off] : 0;
        __syncthreads();
        s[t] += x;
        __syncthreads();
    }
    if (i < NN) ex[i] = s[t] - v;
    if (t == 255) blksum[blockIdx.x] = s[255];
}

__global__ __launch_bounds__(256) void k_scan2(int* __restrict__ blksum) {
    __shared__ int s[256];
    const int t = threadIdx.x;
    int v = (t < NBLK) ? blksum[t] : 0;
    s[t] = v;
    __syncthreads();
    for (int off = 1; off < 256; off <<= 1) {
        int x = (t >= off) ? s[t - off] : 0;
        __syncthreads();
        s[t] += x;
        __syncthreads();
    }
    if (t < NBLK) blksum[t] = s[t] - v;
}

__global__ void k_scan3(const int* __restrict__ ex, const int* __restrict__ blkoff,
                        int* __restrict__ row_ptr, int* __restrict__ cursor) {
    int i = blockIdx.x * 256 + threadIdx.x;
    if (i < NN) {
        int v = ex[i] + blkoff[blockIdx.x];
        row_ptr[i] = v;
        cursor[i] = v;
    }
    if (i == 0) row_ptr[NN] = EE;
}

__global__ void k_scatter(const int* __restrict__ ei, const float* __restrict__ ea,
                          int* __restrict__ cursor, int* __restrict__ src_sorted,
                          float4* __restrict__ ea_s) {
    int e = blockIdx.x * 256 + threadIdx.x;
    if (e >= EE) return;
    int s = ei[e], d = ei[EE + e];
    int p = atomicAdd(&cursor[d], 1);
    src_sorted[p] = s;
    ea_s[p] = make_float4(ea[3 * e], ea[3 * e + 1], ea[3 * e + 2], 0.f);
}

// ---------------- encoder layer 1 (K=8) ----------------
__global__ __launch_bounds__(256) void k_enc1(const float* __restrict__ x, const float* __restrict__ xm,
                                              const float* __restrict__ We1, const float* __restrict__ be1,
                                              float* __restrict__ t, int n) {
    __shared__ float w[8][128];
    __shared__ float b[128];
    int tid = threadIdx.x;
    for (int i = tid; i < 1024; i += 256) w[i >> 7][i & 127] = We1[i];
    if (tid < 128) b[tid] = be1[tid];
    __syncthreads();
    const int c = tid & 127, rp = tid >> 7;
    const int row0 = blockIdx.x * 32;
    for (int i = 0; i < 16; ++i) {
        int r = row0 + rp * 16 + i;
        if (r >= n) break;
        float i0 = x[r * 5 + 0], i1 = x[r * 5 + 1], i2 = x[r * 5 + 2], i3 = x[r * 5 + 3], i4 = x[r * 5 + 4];
        float m0 = xm[r * 3 + 0], m1 = xm[r * 3 + 1], m2 = xm[r * 3 + 2];
        float s = b[c] + i0 * w[0][c] + i1 * w[1][c] + i2 * w[2][c] + i3 * w[3][c] + i4 * w[4][c]
                + m0 * w[5][c] + m1 * w[6][c] + m2 * w[7][c];
        t[(size_t)r * 128 + c] = fmaxf(s, 0.f);
    }
}

// ---------------- main GEMM: 128x128 tile, out[M x 128] = op([A|A2][M x K] @ W[K x 128]) ----------------
// K2: K=256 (A then A2). STATS: per-graph column sums of output -> sum_h (requires sum_h pre-zeroed).
template <bool RELU, bool ACCUM, bool BIAS, bool GTERM, bool K2, bool STATS>
__global__ __launch_bounds__(256) void gemm128(const float* __restrict__ A, const float* __restrict__ A2,
                                               const float* __restrict__ W,
                                               const float* __restrict__ bias, const float* __restrict__ gt,
                                               const int* __restrict__ batch, float* __restrict__ out,
                                               float* __restrict__ sum_h, int M) {
    __shared__ float At[32][132];   // [k][row] transposed A tile (128 rows)
    __shared__ float Wt[32][128];
    const int tid = threadIdx.x;
    const int tr = tid >> 4;        // 0..15
    const int tc = tid & 15;        // 0..15
    const int row0 = blockIdx.x * 128;
    float acc[8][8];
#pragma unroll
    for (int i = 0; i < 8; ++i)
#pragma unroll
        for (int j = 0; j < 8; ++j) acc[i][j] = 0.f;

    const int KTOT = K2 ? 256 : 128;
    for (int kk = 0; kk < KTOT; kk += 32) {
        const float* Asrc = (!K2 || kk < 128) ? A : A2;
        const int kof = (!K2 || kk < 128) ? kk : kk - 128;
#pragma unroll
        for (int i = 0; i < 4; ++i) {
            int idx = tid + i * 256;
            int r = idx >> 3, c4 = (idx & 7) * 4;
            int rr = row0 + r;
            if (rr >= M) rr = M - 1;
            const float4 v = *(const float4*)(Asrc + (size_t)rr * 128 + kof + c4);
            At[c4 + 0][r] = v.x; At[c4 + 1][r] = v.y; At[c4 + 2][r] = v.z; At[c4 + 3][r] = v.w;
        }
#pragma unroll
        for (int i = 0; i < 4; ++i) {
            int idx = tid + i * 256;
            int r = idx >> 5, c4 = (idx & 31) * 4;
            *(float4*)&Wt[r][c4] = *(const float4*)(W + (size_t)(kk + r) * 128 + c4);
        }
        __syncthreads();
#pragma unroll
        for (int k = 0; k < 32; ++k) {
            float4 a0 = *(const float4*)&At[k][tr * 4];
            float4 a1 = *(const float4*)&At[k][64 + tr * 4];
            float4 b0 = *(const float4*)&Wt[k][tc * 4];
            float4 b1 = *(const float4*)&Wt[k][64 + tc * 4];
            float av[8] = {a0.x, a0.y, a0.z, a0.w, a1.x, a1.y, a1.z, a1.w};
            float bv[8] = {b0.x, b0.y, b0.z, b0.w, b1.x, b1.y, b1.z, b1.w};
#pragma unroll
            for (int i = 0; i < 8; ++i)
#pragma unroll
                for (int j = 0; j < 8; ++j) acc[i][j] += av[i] * bv[j];
        }
        __syncthreads();
    }

    float4 bias0, bias1;
    if (BIAS) {
        bias0 = *(const float4*)(bias + tc * 4);
        bias1 = *(const float4*)(bias + 64 + tc * 4);
    }
    int gsl = 0;
    bool uni = true;
    if (STATS) {
        gsl = batch[(row0 < M) ? row0 : (M - 1)];
        int rhi = row0 + 127; if (rhi >= M) rhi = M - 1;
        uni = (gsl == batch[rhi]);
    }
    float colsum[8];
    if (STATS) {
#pragma unroll
        for (int j = 0; j < 8; ++j) colsum[j] = 0.f;
    }
#pragma unroll
    for (int i = 0; i < 8; ++i) {
        int r = row0 + (i >> 2) * 64 + tr * 4 + (i & 3);
        if (r >= M) continue;
        float o[8];
#pragma unroll
        for (int j = 0; j < 8; ++j) o[j] = acc[i][j];
        if (BIAS) {
            o[0] += bias0.x; o[1] += bias0.y; o[2] += bias0.z; o[3] += bias0.w;
            o[4] += bias1.x; o[5] += bias1.y; o[6] += bias1.z; o[7] += bias1.w;
        }
        if (GTERM) {
            int g = batch[r];
            const float4 g0 = *(const float4*)(gt + g * 128 + tc * 4);
            const float4 g1 = *(const float4*)(gt + g * 128 + 64 + tc * 4);
            o[0] += g0.x; o[1] += g0.y; o[2] += g0.z; o[3] += g0.w;
            o[4] += g1.x; o[5] += g1.y; o[6] += g1.z; o[7] += g1.w;
        }
        size_t off0 = (size_t)r * 128 + tc * 4;
        size_t off1 = off0 + 64;
        if (ACCUM) {
            float4 e0 = *(const float4*)(out + off0);
            float4 e1 = *(const float4*)(out + off1);
            o[0] += e0.x; o[1] += e0.y; o[2] += e0.z; o[3] += e0.w;
            o[4] += e1.x; o[5] += e1.y; o[6] += e1.z; o[7] += e1.w;
        }
        if (RELU) {
#pragma unroll
            for (int j = 0; j < 8; ++j) o[j] = fmaxf(o[j], 0.f);
        }
        if (STATS) {
            if (uni) {
#pragma unroll
                for (int j = 0; j < 8; ++j) colsum[j] += o[j];
            } else {
                int g = batch[r];
#pragma unroll
                for (int j = 0; j < 8; ++j) {
                    int col = (j >> 2) * 64 + tc * 4 + (j & 3);
                    atomicAdd(&sum_h[g * 128 + col], o[j]);
                }
            }
        }
        *(float4*)(out + off0) = make_float4(o[0], o[1], o[2], o[3]);
        *(float4*)(out + off1) = make_float4(o[4], o[5], o[6], o[7]);
    }
    if (STATS && uni) {
        float (*sred)[128] = (float(*)[128])Wt;   // reuse Wt LDS
        __syncthreads();
#pragma unroll
        for (int j = 0; j < 8; ++j) {
            int col = (j >> 2) * 64 + tc * 4 + (j & 3);
            sred[tr][col] = colsum[j];
        }
        __syncthreads();
        if (tid < 128) {
            float s = 0.f;
#pragma unroll
            for (int t = 0; t < 16; ++t) s += sred[t][tid];
            atomicAdd(&sum_h[gsl * 128 + tid], s);
        }
    }
}

// ---------------- edge aggregation: one wave per destination node ----------------
__global__ __launch_bounds__(256) void k_edge_agg(const float* __restrict__ Ps, const float* __restrict__ Pd,
                                                  const int* __restrict__ row_ptr, const int* __restrict__ src_sorted,
                                                  const float4* __restrict__ ea_s, const float* __restrict__ Wm1,
                                                  float* __restrict__ accm) {
    const int lane = threadIdx.x & 63;
    const int d = blockIdx.x * 4 + (threadIdx.x >> 6);
    const int c = lane * 2;
    const float2 w0 = *(const float2*)&Wm1[256 * 128 + c];
    const float2 w1 = *(const float2*)&Wm1[257 * 128 + c];
    const float2 w2 = *(const float2*)&Wm1[258 * 128 + c];
    const float2 pd = *(const float2*)&Pd[(size_t)d * 128 + c];
    const int beg = row_ptr[d], end = row_ptr[d + 1];
    const float2 sv = *(const float2*)&Ps[(size_t)d * 128 + c];
    float ax = fmaxf(sv.x + pd.x, 0.f);
    float ay = fmaxf(sv.y + pd.y, 0.f);
    int k = beg;
    for (; k + 1 < end; k += 2) {
        int s0 = src_sorted[k], s1 = src_sorted[k + 1];
        float4 e0 = ea_s[k], e1 = ea_s[k + 1];
        float2 pa = *(const float2*)&Ps[(size_t)s0 * 128 + c];
        float2 pb = *(const float2*)&Ps[(size_t)s1 * 128 + c];
        float px0 = pa.x + pd.x + e0.x * w0.x + e0.y * w1.x + e0.z * w2.x;
        float py0 = pa.y + pd.y + e0.x * w0.y + e0.y * w1.y + e0.z * w2.y;
        float px1 = pb.x + pd.x + e1.x * w0.x + e1.y * w1.x + e1.z * w2.x;
        float py1 = pb.y + pd.y + e1.x * w0.y + e1.y * w1.y + e1.z * w2.y;
        ax += fmaxf(px0, 0.f) + fmaxf(px1, 0.f);
        ay += fmaxf(py0, 0.f) + fmaxf(py1, 0.f);
    }
    if (k < end) {
        int s0 = src_sorted[k];
        float4 e0 = ea_s[k];
        float2 pa = *(const float2*)&Ps[(size_t)s0 * 128 + c];
        float px0 = pa.x + pd.x + e0.x * w0.x + e0.y * w1.x + e0.z * w2.x;
        float py0 = pa.y + pd.y + e0.x * w0.y + e0.y * w1.y + e0.z * w2.y;
        ax += fmaxf(px0, 0.f);
        ay += fmaxf(py0, 0.f);
    }
    float inv = 1.f / (float)(end - beg + 1);
    *(float2*)&accm[(size_t)d * 128 + c] = make_float2(ax * inv, ay * inv);
}

// ---------------- encoder per-graph stats (once): sum_h, sum_hbc, counts ----------------
__global__ __launch_bounds__(256) void k_stats_bc(const float* __restrict__ h, const float* __restrict__ xm,
                                                  const int* __restrict__ batch, float* __restrict__ sum_h,
                                                  float* __restrict__ sum_hbc, float* __restrict__ cnt_node,
                                                  float* __restrict__ cnt_bc) {
    __shared__ float sred[8][128];
    __shared__ float scn[8], scb[8];
    const int t = threadIdx.x;
    const int c4 = (t & 31) * 4;
    const int rsub = t >> 5;   // 0..7
    const int row0 = blockIdx.x * 64;
    int rlo = (row0 < NN) ? row0 : (NN - 1);
    int rhi = (row0 + 63 < NN) ? row0 + 63 : (NN - 1);
    const int gl = batch[rlo];
    const bool uni = (gl == batch[rhi]);
    float4 s = make_float4(0.f, 0.f, 0.f, 0.f), sb = make_float4(0.f, 0.f, 0.f, 0.f);
    float cn = 0.f, cb = 0.f;
#pragma unroll
    for (int ii = 0; ii < 8; ++ii) {
        int r = row0 + ii * 8 + rsub;
        if (r >= NN) continue;
        float4 v = *(const float4*)(h + (size_t)r * 128 + c4);
        float bc = xm[r * 3 + 2];
        if (uni) {
            s.x += v.x; s.y += v.y; s.z += v.z; s.w += v.w;
            sb.x += v.x * bc; sb.y += v.y * bc; sb.z += v.z * bc; sb.w += v.w * bc;
            if ((t & 31) == 0) { cn += 1.f; cb += bc; }
        } else {
            int g = batch[r];
            atomicAdd(&sum_h[g * 128 + c4 + 0], v.x);
            atomicAdd(&sum_h[g * 128 + c4 + 1], v.y);
            atomicAdd(&sum_h[g * 128 + c4 + 2], v.z);
            atomicAdd(&sum_h[g * 128 + c4 + 3], v.w);
            atomicAdd(&sum_hbc[g * 128 + c4 + 0], v.x * bc);
            atomicAdd(&sum_hbc[g * 128 + c4 + 1], v.y * bc);
            atomicAdd(&sum_hbc[g * 128 + c4 + 2], v.z * bc);
            atomicAdd(&sum_hbc[g * 128 + c4 + 3], v.w * bc);
            if ((t & 31) == 0) {
                atomicAdd(&cnt_node[g], 1.f);
                atomicAdd(&cnt_bc[g], bc);
            }
        }
    }
    if (!uni) return;
    *(float4*)&sred[rsub][c4] = s;
    __syncthreads();
    if (t < 128) {
        float tot = 0.f;
#pragma unroll
        for (int q = 0; q < 8; ++q) tot += sred[q][t];
        atomicAdd(&sum_h[gl * 128 + t], tot);
    }
    __syncthreads();
    *(float4*)&sred[rsub][c4] = sb;
    if ((t & 31) == 0) { scn[rsub] = cn; scb[rsub] = cb; }
    __syncthreads();
    if (t < 128) {
        float tot = 0.f;
#pragma unroll
        for (int q = 0; q < 8; ++q) tot += sred[q][t];
        atomicAdd(&sum_hbc[gl * 128 + t], tot);
    }
    if (t == 0) {
        float a = 0.f, b = 0.f;
#pragma unroll
        for (int q = 0; q < 8; ++q) { a += scn[q]; b += scb[q]; }
        atomicAdd(&cnt_node[gl], a);
        atomicAdd(&cnt_bc[gl], b);
    }
}

// gterm[g] = mean_h[g] @ Wu1[256:384] + mean_hbc[g] @ Wu1[384:512]
__global__ __launch_bounds__(128) void k_gterm(const float* __restrict__ sum_h, const float* __restrict__ sum_hbc,
                                               const float* __restrict__ cnt_node, const float* __restrict__ cnt_bc,
                                               const float* __restrict__ Wu1, float* __restrict__ gt) {
    const int g = blockIdx.x;
    const int c = threadIdx.x;
    __shared__ float sg[128], sb[128];
    const float invn = 1.f / fmaxf(cnt_node[g], 1.f);
    const float invb = 1.f / fmaxf(cnt_bc[g], 1.f);
    sg[c] = sum_h[g * 128 + c] * invn;
    sb[c] = sum_hbc[g * 128 + c] * invb;
    __syncthreads();
    float s = 0.f;
    for (int k = 0; k < 128; ++k) s += sg[k] * Wu1[(256 + k) * 128 + c];
    for (int k = 0; k < 128; ++k) s += sb[k] * Wu1[(384 + k) * 128 + c];
    gt[g * 128 + c] = s;
}

// ---------------- decoder layer 2 (128 -> 3), one wave per row ----------------
__global__ __launch_bounds__(256) void k_dec2(const float* __restrict__ t, const float* __restrict__ Wd2,
                                              const float* __restrict__ bd2, float* __restrict__ out, int n) {
    const int lane = threadIdx.x & 63;
    const int r = blockIdx.x * 4 + (threadIdx.x >> 6);
    if (r >= n) return;
    float p0 = 0.f, p1 = 0.f, p2 = 0.f;
    for (int k = lane; k < 128; k += 64) {
        float tv = t[(size_t)r * 128 + k];
        p0 += tv * Wd2[k * 3 + 0];
        p1 += tv * Wd2[k * 3 + 1];
        p2 += tv * Wd2[k * 3 + 2];
    }
    for (int off = 32; off; off >>= 1) {
        p0 += __shfl_down(p0, off);
        p1 += __shfl_down(p1, off);
        p2 += __shfl_down(p2, off);
    }
    if (lane == 0) {
        out[r * 3 + 0] = p0 + bd2[0];
        out[r * 3 + 1] = p1 + bd2[1];
        out[r * 3 + 2] = p2 + bd2[2];
    }
}

extern "C" void kernel_launch(void* const* d_in, const int* in_sizes, int n_in,
                              void* d_out, int out_size, void* d_ws, size_t ws_size,
                              hipStream_t stream) {
    const float* x = (const float*)d_in[0];
    const float* x_mask = (const float*)d_in[1];
    const float* edge_attr = (const float*)d_in[2];
    const float* W_e1 = (const float*)d_in[4];
    const float* b_e1 = (const float*)d_in[5];
    const float* W_e2 = (const float*)d_in[6];
    const float* b_e2 = (const float*)d_in[7];
    const float* W_m1 = (const float*)d_in[8];
    const float* b_m1 = (const float*)d_in[9];
    const float* W_m2 = (const float*)d_in[10];
    const float* b_m2 = (const float*)d_in[11];
    const float* W_u1 = (const float*)d_in[12];
    const float* b_u1 = (const float*)d_in[13];
    const float* W_u2 = (const float*)d_in[14];
    const float* b_u2 = (const float*)d_in[15];
    const float* W_d1 = (const float*)d_in[16];
    const float* b_d1 = (const float*)d_in[17];
    const float* W_d2 = (const float*)d_in[18];
    const float* b_d2 = (const float*)d_in[19];
    const int* edge_index = (const int*)d_in[20];
    const int* batch = (const int*)d_in[21];
    float* out = (float*)d_out;

    char* wp = (char*)d_ws;
    auto carve = [&](size_t bytes) {
        char* r = wp;
        wp += (bytes + 255) & ~(size_t)255;
        return r;
    };
    float* h = (float*)carve(sizeof(float) * (size_t)NN * 128);
    float* Ps = (float*)carve(sizeof(float) * (size_t)NN * 128);
    float* Pd = (float*)carve(sizeof(float) * (size_t)NN * 128);
    float* accm = (float*)carve(sizeof(float) * (size_t)NN * 128);
    float4* ea_s = (float4*)carve(sizeof(float4) * (size_t)EE);
    float* stats = (float*)carve(sizeof(float) * 4096);
    float* sum_h = stats;             // 1024
    float* sum_hbc = stats + 1024;    // 1024
    float* cnt_node = stats + 2048;   // 8
    float* cnt_bc = stats + 2056;     // 8
    float* gterm = stats + 2304;      // 1024
    int* deg = (int*)carve(sizeof(int) * NN);
    int* row_ptr = (int*)carve(sizeof(int) * (NN + 1));
    int* cursor = (int*)carve(sizeof(int) * NN);
    int* src_sorted = (int*)carve(sizeof(int) * EE);
    int* exbuf = (int*)carve(sizeof(int) * NN);
    int* blksum = (int*)carve(sizeof(int) * 256);

    const dim3 b256(256);
    const int gE256 = (EE + 255) / 256;

    hipMemsetAsync(deg, 0, sizeof(int) * NN, stream);
    hipMemsetAsync(stats, 0, sizeof(float) * 2064, stream);
    // CSR
    k_count<<<gE256, b256, 0, stream>>>(edge_index, deg);
    k_scan1<<<NBLK, b256, 0, stream>>>(deg, exbuf, blksum);
    k_scan2<<<1, b256, 0, stream>>>(blksum);
    k_scan3<<<NBLK, b256, 0, stream>>>(exbuf, blksum, row_ptr, cursor);
    k_scatter<<<gE256, b256, 0, stream>>>(edge_index, edge_attr, cursor, src_sorted, ea_s);
    // encoder
    k_enc1<<<(NN + 31) / 32, b256, 0, stream>>>(x, x_mask, W_e1, b_e1, accm, NN);
    gemm128<false, false, true, false, false, false><<<GB128, b256, 0, stream>>>(accm, nullptr, W_e2, b_e2, nullptr, nullptr, h, nullptr, NN);
    // per-graph stats (once): sums for x_graph0, x_BC, counts
    k_stats_bc<<<GB64, b256, 0, stream>>>(h, x_mask, batch, sum_h, sum_hbc, cnt_node, cnt_bc);

    for (int rep = 0; rep < 3; ++rep) {
        k_gterm<<<GG, 128, 0, stream>>>(sum_h, sum_hbc, cnt_node, cnt_bc, W_u1, gterm);
        gemm128<false, false, false, false, false, false><<<GB128, b256, 0, stream>>>(h, nullptr, W_m1, nullptr, nullptr, nullptr, Ps, nullptr, NN);
        gemm128<false, false, true, false, false, false><<<GB128, b256, 0, stream>>>(h, nullptr, W_m1 + 128 * 128, b_m1, nullptr, nullptr, Pd, nullptr, NN);
        k_edge_agg<<<NN / 4, b256, 0, stream>>>(Ps, Pd, row_ptr, src_sorted, ea_s, W_m1, accm);
        // agg = accm @ W_m2 + b_m2 -> Ps
        gemm128<false, false, true, false, false, false><<<GB128, b256, 0, stream>>>(accm, nullptr, W_m2, b_m2, nullptr, nullptr, Ps, nullptr, NN);
        // pre = relu([h|agg] @ Wu1[0:256] + gterm[batch] + b_u1) -> Pd
        gemm128<true, false, true, true, true, false><<<GB128, b256, 0, stream>>>(h, Ps, W_u1, b_u1, gterm, batch, Pd, nullptr, NN);
        // h += pre @ Wu2 + bu2, with fused per-graph column sums for next rep's gterm
        if (rep < 2) {
            hipMemsetAsync(sum_h, 0, sizeof(float) * 1024, stream);
            gemm128<false, true, true, false, false, true><<<GB128, b256, 0, stream>>>(Pd, nullptr, W_u2, b_u2, nullptr, batch, h, sum_h, NN);
        } else {
            gemm128<false, true, true, false, false, false><<<GB128, b256, 0, stream>>>(Pd, nullptr, W_u2, b_u2, nullptr, batch, h, nullptr, NN);
        }
    }
    // decoder
    gemm128<true, false, true, false, false, false><<<GB128, b256, 0, stream>>>(h, nullptr, W_d1, b_d1, nullptr, nullptr, accm, nullptr, NN);
    k_dec2<<<NN / 4, b256, 0, stream>>>(accm, W_d2, b_d2, out, NN);
}